// Round 8
// baseline (225.074 us; speedup 1.0000x reference)
//
#include <hip/hip_runtime.h>
#include <math.h>
#include <type_traits>

#define CC 62
#define TT 1000
#define HH 14
#define NPAIR 105      // 14*15/2 upper-triangle pairs
#define SSTRIDE 112    // ws stride per element (105 used, padded)
#define NCHEB 20       // Chebyshev terms (degree 19), closed-form coefs
// log(x) on [0.25, 2.0]:  log(c + d*y), c=1.125, d=0.875, y in [-1,1]
// A = (c + sqrt(c^2-d^2))/2, r = -d/(2A);  log = logA - 2*sum_k (r^k/k) T_k(y)
#define LOG_A  (-0.08768183236702332f)
#define CH_R   (-0.47759225007251715f)

// ---- compile-time for: guarantees constant array indices (no scratch) ----
template <int N, typename F>
__device__ __forceinline__ void static_for(F&& f) {
    if constexpr (N > 0) {
        static_for<N - 1>(f);
        f(std::integral_constant<int, N - 1>{});
    }
}
template <int V> using ic = std::integral_constant<int, V>;

constexpr int pair_i(int p) {
    int i = 0;
    while (p >= HH - i) { p -= HH - i; ++i; }
    return i;
}
constexpr int pair_j(int p) {
    int i = 0;
    while (p >= HH - i) { p -= HH - i; ++i; }
    return i + p;
}

// ---- wave64 sum via DPP (VALU pipe only, no LDS traffic) ----
// Hillis-Steele within 16-lane rows, then bcast15/bcast31 to combine rows.
// Full sum lands in lane 63.
__device__ __forceinline__ float wred(float v) {
    int m;
    m = __builtin_amdgcn_update_dpp(0, __float_as_int(v), 0x111, 0xf, 0xf, false); // row_shr:1
    v += __int_as_float(m);
    m = __builtin_amdgcn_update_dpp(0, __float_as_int(v), 0x112, 0xf, 0xf, false); // row_shr:2
    v += __int_as_float(m);
    m = __builtin_amdgcn_update_dpp(0, __float_as_int(v), 0x114, 0xf, 0xf, false); // row_shr:4
    v += __int_as_float(m);
    m = __builtin_amdgcn_update_dpp(0, __float_as_int(v), 0x118, 0xf, 0xf, false); // row_shr:8
    v += __int_as_float(m);
    m = __builtin_amdgcn_update_dpp(0, __float_as_int(v), 0x142, 0xa, 0xf, false); // row_bcast15 -> rows 1,3
    v += __int_as_float(m);
    m = __builtin_amdgcn_update_dpp(0, __float_as_int(v), 0x143, 0xc, 0xf, false); // row_bcast31 -> rows 2,3
    v += __int_as_float(m);
    return v;
}

// ================= kernel 1: stream + Gram -> S (ws) =================
// launch_bounds(256,5): 20 waves/CU (VGPR cap 102; measured need ~90).
__global__ __launch_bounds__(256, 5) void spd_gram(
    const float* __restrict__ x,
    const float* __restrict__ w1,
    float* __restrict__ Sout)
{
    const int b    = blockIdx.x;
    const int tid  = threadIdx.x;
    const int lane = tid & 63;
    const int wv   = tid >> 6;

    __shared__ float wpart[4][NPAIR + HH];

    const int t = tid * 4;
    const bool act = (t < TT);                 // tid < 250 active
    const float* xt = x + (size_t)b * (CC * TT) + t;

    float4 buf[3][4];                          // compile-time indices -> regs
    float z0[HH], z1[HH], z2[HH], z3[HH];
    static_for<HH>([&](auto H_) {
        constexpr int h = H_.value;
        z0[h] = 0.f; z1[h] = 0.f; z2[h] = 0.f; z3[h] = 0.f;
    });

    auto loadg = [&](auto Gc) {
        constexpr int g  = Gc.value;
        constexpr int bs = g % 3;
        constexpr int nr = (g == 15) ? 2 : 4;
        static_for<nr>([&](auto CI) {
            constexpr int ci = CI.value;
            buf[bs][ci] = *(const float4*)(xt + (size_t)(4 * g + ci) * TT);
        });
    };
    auto computeg = [&](auto Gc) {
        constexpr int g  = Gc.value;
        constexpr int bs = g % 3;
        constexpr int nr = (g == 15) ? 2 : 4;
        static_for<nr>([&](auto CI) {
            constexpr int ci = CI.value;
            const float* wr = w1 + (4 * g + ci) * HH;
            const float4 xv = buf[bs][ci];
            static_for<HH>([&](auto H_) {
                constexpr int h = H_.value;
                const float w = wr[h];         // wave-uniform -> scalar load
                z0[h] = fmaf(w, xv.x, z0[h]);
                z1[h] = fmaf(w, xv.y, z1[h]);
                z2[h] = fmaf(w, xv.z, z2[h]);
                z3[h] = fmaf(w, xv.w, z3[h]);
            });
        });
    };

    if (act) {
        loadg(ic<0>{});
        loadg(ic<1>{});
        static_for<16>([&](auto Gc) {          // loads 2 groups ahead
            constexpr int g = Gc.value;
            if constexpr (g + 2 <= 15) loadg(ic<g + 2>{});
            computeg(Gc);
        });
    }

    // ---- Gram pairs + DPP wave reduce (no LDS-pipe shuffles) ----
    static_for<NPAIR>([&](auto P) {
        constexpr int p = P.value;
        constexpr int i = pair_i(p);
        constexpr int j = pair_j(p);
        float v = z0[i] * z0[j];
        v = fmaf(z1[i], z1[j], v);
        v = fmaf(z2[i], z2[j], v);
        v = fmaf(z3[i], z3[j], v);
        v = wred(v);
        if (lane == 63) wpart[wv][p] = v;
    });
    static_for<HH>([&](auto H_) {
        constexpr int h = H_.value;
        float v = z0[h] + z1[h] + z2[h] + z3[h];
        v = wred(v);
        if (lane == 63) wpart[wv][NPAIR + h] = v;
    });
    __syncthreads();

    if (tid < NPAIR) {
        float g = wpart[0][tid] + wpart[1][tid] + wpart[2][tid] + wpart[3][tid];
        int i = 0, rem = tid;
        while (rem >= HH - i) { rem -= HH - i; ++i; }
        int j = i + rem;
        float mi = wpart[0][NPAIR+i] + wpart[1][NPAIR+i] + wpart[2][NPAIR+i] + wpart[3][NPAIR+i];
        float mj = wpart[0][NPAIR+j] + wpart[1][NPAIR+j] + wpart[2][NPAIR+j] + wpart[3][NPAIR+j];
        float s = g * (1.0f / TT) - mi * mj * (1.0f / ((float)TT * (float)TT));
        Sout[(size_t)b * SSTRIDE + tid] = s;
    }
}

// ================= kernel 2: Clenshaw logm + Q^T L Q + FC =================
__global__ __launch_bounds__(256, 4) void spd_tail(
    const float* __restrict__ Sin,
    const float* __restrict__ w2,
    const float* __restrict__ w3,
    const float* __restrict__ fcw,
    const float* __restrict__ fcb,
    float* __restrict__ out)
{
    const int b    = blockIdx.x;
    const int tid  = threadIdx.x;
    const int lane = tid & 63;
    const int wv   = tid >> 6;

    __shared__ float coef[NCHEB];
    __shared__ float Qm[196];          // w2 @ w3
    __shared__ float Sm[196];          // s1
    __shared__ float Ym[196];          // scaled Clenshaw argument
    __shared__ float Bufs[3][196];     // Clenshaw b_k buffers
    __shared__ float Lm[196];          // logm(s1)
    __shared__ float Tm[196];          // L @ Q
    __shared__ float Fm[196];          // Q^T L Q
    __shared__ float lpart[4][2];

    if (tid == 0) {
        coef[0] = 2.0f * LOG_A;            // Clenshaw adds 0.5*coef[0]
        float rk = 1.0f;
        for (int k = 1; k < NCHEB; ++k) {
            rk *= CH_R;
            coef[k] = -2.0f * rk / (float)k;
        }
    }
    if (tid < 196) {
        int i = tid / 14, j = tid % 14;
        float acc = 0.f;
        #pragma unroll
        for (int k = 0; k < 14; ++k) acc = fmaf(w2[i*14 + k], w3[k*14 + j], acc);
        Qm[tid] = acc;
    }
    if (tid < NPAIR) {
        float s = Sin[(size_t)b * SSTRIDE + tid];
        int i = 0, rem = tid;
        while (rem >= HH - i) { rem -= HH - i; ++i; }
        int j = i + rem;
        Sm[i*14 + j] = s;
        Sm[j*14 + i] = s;
    }
    __syncthreads();

    // Y = (2 S - (a+b) I) / (b-a); init Clenshaw buffers
    if (tid < 196) {
        int i = tid / 14, j = tid % 14;
        float d = (i == j) ? 1.f : 0.f;
        Ym[tid] = (2.0f * Sm[tid] - 2.25f * d) * (1.0f / 1.75f);
        Bufs[0][tid] = 0.f;
        Bufs[1][tid] = 0.f;
    }
    __syncthreads();

    // Clenshaw: logm(s1) = 0.5 c0 I + sum c_k T_k(Y)
    int ib1 = 0, ib2 = 1, ibn = 2;
    for (int k = NCHEB - 1; k >= 1; --k) {
        if (tid < 196) {
            int i = tid / 14, j = tid % 14;
            float acc = 0.f;
            #pragma unroll
            for (int kk = 0; kk < 14; ++kk)
                acc = fmaf(Ym[i*14 + kk], Bufs[ib1][kk*14 + j], acc);
            Bufs[ibn][tid] = 2.0f * acc - Bufs[ib2][tid] + ((i == j) ? coef[k] : 0.f);
        }
        __syncthreads();
        int t0 = ib2; ib2 = ib1; ib1 = ibn; ibn = t0;
    }
    if (tid < 196) {
        int i = tid / 14, j = tid % 14;
        float acc = 0.f;
        #pragma unroll
        for (int kk = 0; kk < 14; ++kk)
            acc = fmaf(Ym[i*14 + kk], Bufs[ib1][kk*14 + j], acc);
        Lm[tid] = acc - Bufs[ib2][tid] + ((i == j) ? 0.5f * coef[0] : 0.f);
    }
    __syncthreads();

    // F = Q^T L Q
    if (tid < 196) {
        int i = tid / 14, j = tid % 14;
        float acc = 0.f;
        #pragma unroll
        for (int kk = 0; kk < 14; ++kk)
            acc = fmaf(Lm[i*14 + kk], Qm[kk*14 + j], acc);
        Tm[tid] = acc;
    }
    __syncthreads();
    if (tid < 196) {
        int i = tid / 14, j = tid % 14;
        float acc = 0.f;
        #pragma unroll
        for (int kk = 0; kk < 14; ++kk)
            acc = fmaf(Qm[kk*14 + i], Tm[kk*14 + j], acc);
        Fm[tid] = acc;
    }
    __syncthreads();

    // logits + sigmoid
    float v0 = 0.f, v1 = 0.f;
    if (tid < 196) {
        float f = Fm[tid];
        v0 = f * fcw[tid];
        v1 = f * fcw[196 + tid];
    }
    v0 += __shfl_down(v0, 32, 64);  v1 += __shfl_down(v1, 32, 64);
    v0 += __shfl_down(v0, 16, 64);  v1 += __shfl_down(v1, 16, 64);
    v0 += __shfl_down(v0,  8, 64);  v1 += __shfl_down(v1,  8, 64);
    v0 += __shfl_down(v0,  4, 64);  v1 += __shfl_down(v1,  4, 64);
    v0 += __shfl_down(v0,  2, 64);  v1 += __shfl_down(v1,  2, 64);
    v0 += __shfl_down(v0,  1, 64);  v1 += __shfl_down(v1,  1, 64);
    if (lane == 0) { lpart[wv][0] = v0; lpart[wv][1] = v1; }
    __syncthreads();
    if (tid == 0) {
        float l0 = lpart[0][0] + lpart[1][0] + lpart[2][0] + lpart[3][0] + fcb[0];
        float l1 = lpart[0][1] + lpart[1][1] + lpart[2][1] + lpart[3][1] + fcb[1];
        out[b*2 + 0] = 1.0f / (1.0f + expf(-l0));
        out[b*2 + 1] = 1.0f / (1.0f + expf(-l1));
    }
}

extern "C" void kernel_launch(void* const* d_in, const int* in_sizes, int n_in,
                              void* d_out, int out_size, void* d_ws, size_t ws_size,
                              hipStream_t stream) {
    const float* x   = (const float*)d_in[0];
    const float* w1  = (const float*)d_in[1];
    const float* w2  = (const float*)d_in[2];
    const float* w3  = (const float*)d_in[3];
    const float* fcw = (const float*)d_in[4];
    const float* fcb = (const float*)d_in[5];
    float* out = (float*)d_out;
    float* Sws = (float*)d_ws;                 // B * SSTRIDE floats
    int B = in_sizes[0] / (CC * TT);
    spd_gram<<<B, 256, 0, stream>>>(x, w1, Sws);
    spd_tail<<<B, 256, 0, stream>>>(Sws, w2, w3, fcw, fcb, out);
}

// Round 9
// 180.777 us; speedup vs baseline: 1.2450x; 1.2450x over previous
//
#include <hip/hip_runtime.h>
#include <math.h>
#include <type_traits>

#define CC 62
#define TT 1000
#define HH 14
#define NPAIR 105      // 14*15/2 upper-triangle pairs
#define SSTRIDE 112    // ws stride per element (105 used, padded)
#define NCHEB 20       // Chebyshev terms (degree 19), closed-form coefs
// log(x) on [0.25, 2.0]:  log(c + d*y), c=1.125, d=0.875, y in [-1,1]
// A = (c + sqrt(c^2-d^2))/2, r = -d/(2A);  log = logA - 2*sum_k (r^k/k) T_k(y)
#define LOG_A  (-0.08768183236702332f)
#define CH_R   (-0.47759225007251715f)

// ---- compile-time for: guarantees constant array indices (no scratch) ----
template <int N, typename F>
__device__ __forceinline__ void static_for(F&& f) {
    if constexpr (N > 0) {
        static_for<N - 1>(f);
        f(std::integral_constant<int, N - 1>{});
    }
}
template <int V> using ic = std::integral_constant<int, V>;

constexpr int pair_i(int p) {
    int i = 0;
    while (p >= HH - i) { p -= HH - i; ++i; }
    return i;
}
constexpr int pair_j(int p) {
    int i = 0;
    while (p >= HH - i) { p -= HH - i; ++i; }
    return i + p;
}

// ---- wave64 sum via DPP (VALU pipe only, no LDS traffic) ----
// Hillis-Steele within 16-lane rows, then bcast15/bcast31 to combine rows.
// Full sum lands in lane 63.
__device__ __forceinline__ float wred(float v) {
    int m;
    m = __builtin_amdgcn_update_dpp(0, __float_as_int(v), 0x111, 0xf, 0xf, false); // row_shr:1
    v += __int_as_float(m);
    m = __builtin_amdgcn_update_dpp(0, __float_as_int(v), 0x112, 0xf, 0xf, false); // row_shr:2
    v += __int_as_float(m);
    m = __builtin_amdgcn_update_dpp(0, __float_as_int(v), 0x114, 0xf, 0xf, false); // row_shr:4
    v += __int_as_float(m);
    m = __builtin_amdgcn_update_dpp(0, __float_as_int(v), 0x118, 0xf, 0xf, false); // row_shr:8
    v += __int_as_float(m);
    m = __builtin_amdgcn_update_dpp(0, __float_as_int(v), 0x142, 0xa, 0xf, false); // row_bcast15 -> rows 1,3
    v += __int_as_float(m);
    m = __builtin_amdgcn_update_dpp(0, __float_as_int(v), 0x143, 0xc, 0xf, false); // row_bcast31 -> rows 2,3
    v += __int_as_float(m);
    return v;
}

// ================= kernel 1: stream + Gram -> S (ws) =================
// launch_bounds(256,5): 20 waves/CU. Register budget: 512/5 = 102 VGPR.
// Pipeline sized to fit: 2-row groups, 4-buffer rotation (32 VGPR bufs),
// loads 3 groups ahead (6 KB/wave in flight; lead ~3400 cyc > HBM ~2200).
__global__ __launch_bounds__(256, 5) void spd_gram(
    const float* __restrict__ x,
    const float* __restrict__ w1,
    float* __restrict__ Sout)
{
    const int b    = blockIdx.x;
    const int tid  = threadIdx.x;
    const int lane = tid & 63;
    const int wv   = tid >> 6;

    __shared__ float wpart[4][NPAIR + HH];

    const int t = tid * 4;
    const bool act = (t < TT);                 // tid < 250 active
    const float* xt = x + (size_t)b * (CC * TT) + t;

    float4 buf[4][2];                          // compile-time indices -> regs
    float z0[HH], z1[HH], z2[HH], z3[HH];
    static_for<HH>([&](auto H_) {
        constexpr int h = H_.value;
        z0[h] = 0.f; z1[h] = 0.f; z2[h] = 0.f; z3[h] = 0.f;
    });

    auto loadg = [&](auto Gc) {                // group g = rows {2g, 2g+1}
        constexpr int g  = Gc.value;
        constexpr int bs = g % 4;
        static_for<2>([&](auto CI) {
            constexpr int ci = CI.value;
            buf[bs][ci] = *(const float4*)(xt + (size_t)(2 * g + ci) * TT);
        });
    };
    auto computeg = [&](auto Gc) {
        constexpr int g  = Gc.value;
        constexpr int bs = g % 4;
        static_for<2>([&](auto CI) {
            constexpr int ci = CI.value;
            const float* wr = w1 + (2 * g + ci) * HH;
            const float4 xv = buf[bs][ci];
            static_for<HH>([&](auto H_) {
                constexpr int h = H_.value;
                const float w = wr[h];         // wave-uniform -> scalar load
                z0[h] = fmaf(w, xv.x, z0[h]);
                z1[h] = fmaf(w, xv.y, z1[h]);
                z2[h] = fmaf(w, xv.z, z2[h]);
                z3[h] = fmaf(w, xv.w, z3[h]);
            });
        });
    };

    if (act) {
        loadg(ic<0>{});
        loadg(ic<1>{});
        loadg(ic<2>{});
        static_for<31>([&](auto Gc) {          // loads 3 groups ahead
            constexpr int g = Gc.value;
            if constexpr (g + 3 <= 30) loadg(ic<g + 3>{});
            computeg(Gc);
        });
    }

    // ---- Gram pairs + DPP wave reduce (no LDS-pipe shuffles) ----
    static_for<NPAIR>([&](auto P) {
        constexpr int p = P.value;
        constexpr int i = pair_i(p);
        constexpr int j = pair_j(p);
        float v = z0[i] * z0[j];
        v = fmaf(z1[i], z1[j], v);
        v = fmaf(z2[i], z2[j], v);
        v = fmaf(z3[i], z3[j], v);
        v = wred(v);
        if (lane == 63) wpart[wv][p] = v;
    });
    static_for<HH>([&](auto H_) {
        constexpr int h = H_.value;
        float v = z0[h] + z1[h] + z2[h] + z3[h];
        v = wred(v);
        if (lane == 63) wpart[wv][NPAIR + h] = v;
    });
    __syncthreads();

    if (tid < NPAIR) {
        float g = wpart[0][tid] + wpart[1][tid] + wpart[2][tid] + wpart[3][tid];
        int i = 0, rem = tid;
        while (rem >= HH - i) { rem -= HH - i; ++i; }
        int j = i + rem;
        float mi = wpart[0][NPAIR+i] + wpart[1][NPAIR+i] + wpart[2][NPAIR+i] + wpart[3][NPAIR+i];
        float mj = wpart[0][NPAIR+j] + wpart[1][NPAIR+j] + wpart[2][NPAIR+j] + wpart[3][NPAIR+j];
        float s = g * (1.0f / TT) - mi * mj * (1.0f / ((float)TT * (float)TT));
        Sout[(size_t)b * SSTRIDE + tid] = s;
    }
}

// ================= kernel 2: Clenshaw logm + Q^T L Q + FC =================
__global__ __launch_bounds__(256, 4) void spd_tail(
    const float* __restrict__ Sin,
    const float* __restrict__ w2,
    const float* __restrict__ w3,
    const float* __restrict__ fcw,
    const float* __restrict__ fcb,
    float* __restrict__ out)
{
    const int b    = blockIdx.x;
    const int tid  = threadIdx.x;
    const int lane = tid & 63;
    const int wv   = tid >> 6;

    __shared__ float coef[NCHEB];
    __shared__ float Qm[196];          // w2 @ w3
    __shared__ float Sm[196];          // s1
    __shared__ float Ym[196];          // scaled Clenshaw argument
    __shared__ float Bufs[3][196];     // Clenshaw b_k buffers
    __shared__ float Lm[196];          // logm(s1)
    __shared__ float Tm[196];          // L @ Q
    __shared__ float Fm[196];          // Q^T L Q
    __shared__ float lpart[4][2];

    if (tid == 0) {
        coef[0] = 2.0f * LOG_A;            // Clenshaw adds 0.5*coef[0]
        float rk = 1.0f;
        for (int k = 1; k < NCHEB; ++k) {
            rk *= CH_R;
            coef[k] = -2.0f * rk / (float)k;
        }
    }
    if (tid < 196) {
        int i = tid / 14, j = tid % 14;
        float acc = 0.f;
        #pragma unroll
        for (int k = 0; k < 14; ++k) acc = fmaf(w2[i*14 + k], w3[k*14 + j], acc);
        Qm[tid] = acc;
    }
    if (tid < NPAIR) {
        float s = Sin[(size_t)b * SSTRIDE + tid];
        int i = 0, rem = tid;
        while (rem >= HH - i) { rem -= HH - i; ++i; }
        int j = i + rem;
        Sm[i*14 + j] = s;
        Sm[j*14 + i] = s;
    }
    __syncthreads();

    // Y = (2 S - (a+b) I) / (b-a); init Clenshaw buffers
    if (tid < 196) {
        int i = tid / 14, j = tid % 14;
        float d = (i == j) ? 1.f : 0.f;
        Ym[tid] = (2.0f * Sm[tid] - 2.25f * d) * (1.0f / 1.75f);
        Bufs[0][tid] = 0.f;
        Bufs[1][tid] = 0.f;
    }
    __syncthreads();

    // Clenshaw: logm(s1) = 0.5 c0 I + sum c_k T_k(Y)
    int ib1 = 0, ib2 = 1, ibn = 2;
    for (int k = NCHEB - 1; k >= 1; --k) {
        if (tid < 196) {
            int i = tid / 14, j = tid % 14;
            float acc = 0.f;
            #pragma unroll
            for (int kk = 0; kk < 14; ++kk)
                acc = fmaf(Ym[i*14 + kk], Bufs[ib1][kk*14 + j], acc);
            Bufs[ibn][tid] = 2.0f * acc - Bufs[ib2][tid] + ((i == j) ? coef[k] : 0.f);
        }
        __syncthreads();
        int t0 = ib2; ib2 = ib1; ib1 = ibn; ibn = t0;
    }
    if (tid < 196) {
        int i = tid / 14, j = tid % 14;
        float acc = 0.f;
        #pragma unroll
        for (int kk = 0; kk < 14; ++kk)
            acc = fmaf(Ym[i*14 + kk], Bufs[ib1][kk*14 + j], acc);
        Lm[tid] = acc - Bufs[ib2][tid] + ((i == j) ? 0.5f * coef[0] : 0.f);
    }
    __syncthreads();

    // F = Q^T L Q
    if (tid < 196) {
        int i = tid / 14, j = tid % 14;
        float acc = 0.f;
        #pragma unroll
        for (int kk = 0; kk < 14; ++kk)
            acc = fmaf(Lm[i*14 + kk], Qm[kk*14 + j], acc);
        Tm[tid] = acc;
    }
    __syncthreads();
    if (tid < 196) {
        int i = tid / 14, j = tid % 14;
        float acc = 0.f;
        #pragma unroll
        for (int kk = 0; kk < 14; ++kk)
            acc = fmaf(Qm[kk*14 + i], Tm[kk*14 + j], acc);
        Fm[tid] = acc;
    }
    __syncthreads();

    // logits + sigmoid
    float v0 = 0.f, v1 = 0.f;
    if (tid < 196) {
        float f = Fm[tid];
        v0 = f * fcw[tid];
        v1 = f * fcw[196 + tid];
    }
    v0 += __shfl_down(v0, 32, 64);  v1 += __shfl_down(v1, 32, 64);
    v0 += __shfl_down(v0, 16, 64);  v1 += __shfl_down(v1, 16, 64);
    v0 += __shfl_down(v0,  8, 64);  v1 += __shfl_down(v1,  8, 64);
    v0 += __shfl_down(v0,  4, 64);  v1 += __shfl_down(v1,  4, 64);
    v0 += __shfl_down(v0,  2, 64);  v1 += __shfl_down(v1,  2, 64);
    v0 += __shfl_down(v0,  1, 64);  v1 += __shfl_down(v1,  1, 64);
    if (lane == 0) { lpart[wv][0] = v0; lpart[wv][1] = v1; }
    __syncthreads();
    if (tid == 0) {
        float l0 = lpart[0][0] + lpart[1][0] + lpart[2][0] + lpart[3][0] + fcb[0];
        float l1 = lpart[0][1] + lpart[1][1] + lpart[2][1] + lpart[3][1] + fcb[1];
        out[b*2 + 0] = 1.0f / (1.0f + expf(-l0));
        out[b*2 + 1] = 1.0f / (1.0f + expf(-l1));
    }
}

extern "C" void kernel_launch(void* const* d_in, const int* in_sizes, int n_in,
                              void* d_out, int out_size, void* d_ws, size_t ws_size,
                              hipStream_t stream) {
    const float* x   = (const float*)d_in[0];
    const float* w1  = (const float*)d_in[1];
    const float* w2  = (const float*)d_in[2];
    const float* w3  = (const float*)d_in[3];
    const float* fcw = (const float*)d_in[4];
    const float* fcb = (const float*)d_in[5];
    float* out = (float*)d_out;
    float* Sws = (float*)d_ws;                 // B * SSTRIDE floats
    int B = in_sizes[0] / (CC * TT);
    spd_gram<<<B, 256, 0, stream>>>(x, w1, Sws);
    spd_tail<<<B, 256, 0, stream>>>(Sws, w2, w3, fcw, fcb, out);
}

// Round 10
// 123.400 us; speedup vs baseline: 1.8239x; 1.4650x over previous
//
#include <hip/hip_runtime.h>
#include <math.h>
#include <type_traits>

#define CC 62
#define TT 1000
#define HH 14
#define NPAIR 105      // 14*15/2 upper-triangle pairs
#define SSTRIDE 112    // ws stride per element (105 used, padded)
#define NCHEB 12       // Chebyshev terms (degree 11): trunc err ~4.5e-5 << 1.06e-2 threshold
// log(x) on [0.25, 2.0]:  log(c + d*y), c=1.125, d=0.875, y in [-1,1]
// A = (c + sqrt(c^2-d^2))/2, r = -d/(2A);  log = logA - 2*sum_k (r^k/k) T_k(y)
#define LOG_A  (-0.08768183236702332f)
#define CH_R   (-0.47759225007251715f)

// ---- compile-time for: guarantees constant array indices (no scratch) ----
template <int N, typename F>
__device__ __forceinline__ void static_for(F&& f) {
    if constexpr (N > 0) {
        static_for<N - 1>(f);
        f(std::integral_constant<int, N - 1>{});
    }
}
template <int V> using ic = std::integral_constant<int, V>;

constexpr int pair_i(int p) {
    int i = 0;
    while (p >= HH - i) { p -= HH - i; ++i; }
    return i;
}
constexpr int pair_j(int p) {
    int i = 0;
    while (p >= HH - i) { p -= HH - i; ++i; }
    return i + p;
}

// ---- wave64 sum via DPP (VALU pipe only, no LDS traffic) ----
__device__ __forceinline__ float wred(float v) {
    int m;
    m = __builtin_amdgcn_update_dpp(0, __float_as_int(v), 0x111, 0xf, 0xf, false); // row_shr:1
    v += __int_as_float(m);
    m = __builtin_amdgcn_update_dpp(0, __float_as_int(v), 0x112, 0xf, 0xf, false); // row_shr:2
    v += __int_as_float(m);
    m = __builtin_amdgcn_update_dpp(0, __float_as_int(v), 0x114, 0xf, 0xf, false); // row_shr:4
    v += __int_as_float(m);
    m = __builtin_amdgcn_update_dpp(0, __float_as_int(v), 0x118, 0xf, 0xf, false); // row_shr:8
    v += __int_as_float(m);
    m = __builtin_amdgcn_update_dpp(0, __float_as_int(v), 0x142, 0xa, 0xf, false); // row_bcast15 -> rows 1,3
    v += __int_as_float(m);
    m = __builtin_amdgcn_update_dpp(0, __float_as_int(v), 0x143, 0xc, 0xf, false); // row_bcast31 -> rows 2,3
    v += __int_as_float(m);
    return v;
}

// ================= kernel 1: stream + Gram -> S (ws) =================
// EXACT round-7 winner: (256,4), 4-row groups, 3-buffer rotation, depth-2.
// (256,5) regressed twice (r8 spill, r9 fine-grained stalls) -- do not retry.
__global__ __launch_bounds__(256, 4) void spd_gram(
    const float* __restrict__ x,
    const float* __restrict__ w1,
    float* __restrict__ Sout)
{
    const int b    = blockIdx.x;
    const int tid  = threadIdx.x;
    const int lane = tid & 63;
    const int wv   = tid >> 6;

    __shared__ float wpart[4][NPAIR + HH];

    const int t = tid * 4;
    const bool act = (t < TT);                 // tid < 250 active
    const float* xt = x + (size_t)b * (CC * TT) + t;

    float4 buf[3][4];                          // compile-time indices -> regs
    float z0[HH], z1[HH], z2[HH], z3[HH];
    static_for<HH>([&](auto H_) {
        constexpr int h = H_.value;
        z0[h] = 0.f; z1[h] = 0.f; z2[h] = 0.f; z3[h] = 0.f;
    });

    auto loadg = [&](auto Gc) {
        constexpr int g  = Gc.value;
        constexpr int bs = g % 3;
        constexpr int nr = (g == 15) ? 2 : 4;
        static_for<nr>([&](auto CI) {
            constexpr int ci = CI.value;
            buf[bs][ci] = *(const float4*)(xt + (size_t)(4 * g + ci) * TT);
        });
    };
    auto computeg = [&](auto Gc) {
        constexpr int g  = Gc.value;
        constexpr int bs = g % 3;
        constexpr int nr = (g == 15) ? 2 : 4;
        static_for<nr>([&](auto CI) {
            constexpr int ci = CI.value;
            const float* wr = w1 + (4 * g + ci) * HH;
            const float4 xv = buf[bs][ci];
            static_for<HH>([&](auto H_) {
                constexpr int h = H_.value;
                const float w = wr[h];         // wave-uniform -> scalar load
                z0[h] = fmaf(w, xv.x, z0[h]);
                z1[h] = fmaf(w, xv.y, z1[h]);
                z2[h] = fmaf(w, xv.z, z2[h]);
                z3[h] = fmaf(w, xv.w, z3[h]);
            });
        });
    };

    if (act) {
        loadg(ic<0>{});
        loadg(ic<1>{});
        static_for<16>([&](auto Gc) {          // loads 2 groups ahead
            constexpr int g = Gc.value;
            if constexpr (g + 2 <= 15) loadg(ic<g + 2>{});
            computeg(Gc);
        });
    }

    // ---- Gram pairs + DPP wave reduce (no LDS-pipe shuffles) ----
    static_for<NPAIR>([&](auto P) {
        constexpr int p = P.value;
        constexpr int i = pair_i(p);
        constexpr int j = pair_j(p);
        float v = z0[i] * z0[j];
        v = fmaf(z1[i], z1[j], v);
        v = fmaf(z2[i], z2[j], v);
        v = fmaf(z3[i], z3[j], v);
        v = wred(v);
        if (lane == 63) wpart[wv][p] = v;
    });
    static_for<HH>([&](auto H_) {
        constexpr int h = H_.value;
        float v = z0[h] + z1[h] + z2[h] + z3[h];
        v = wred(v);
        if (lane == 63) wpart[wv][NPAIR + h] = v;
    });
    __syncthreads();

    if (tid < NPAIR) {
        float g = wpart[0][tid] + wpart[1][tid] + wpart[2][tid] + wpart[3][tid];
        int i = 0, rem = tid;
        while (rem >= HH - i) { rem -= HH - i; ++i; }
        int j = i + rem;
        float mi = wpart[0][NPAIR+i] + wpart[1][NPAIR+i] + wpart[2][NPAIR+i] + wpart[3][NPAIR+i];
        float mj = wpart[0][NPAIR+j] + wpart[1][NPAIR+j] + wpart[2][NPAIR+j] + wpart[3][NPAIR+j];
        float s = g * (1.0f / TT) - mi * mj * (1.0f / ((float)TT * (float)TT));
        Sout[(size_t)b * SSTRIDE + tid] = s;
    }
}

// ================= kernel 2: Clenshaw logm + Q^T L Q + FC =================
__global__ __launch_bounds__(256, 4) void spd_tail(
    const float* __restrict__ Sin,
    const float* __restrict__ w2,
    const float* __restrict__ w3,
    const float* __restrict__ fcw,
    const float* __restrict__ fcb,
    float* __restrict__ out)
{
    const int b    = blockIdx.x;
    const int tid  = threadIdx.x;
    const int lane = tid & 63;
    const int wv   = tid >> 6;

    __shared__ float coef[NCHEB];
    __shared__ float Qm[196];          // w2 @ w3
    __shared__ float Sm[196];          // s1
    __shared__ float Ym[196];          // scaled Clenshaw argument
    __shared__ float Bufs[3][196];     // Clenshaw b_k buffers
    __shared__ float Lm[196];          // logm(s1)
    __shared__ float Tm[196];          // L @ Q
    __shared__ float Fm[196];          // Q^T L Q
    __shared__ float lpart[4][2];

    if (tid == 0) {
        coef[0] = 2.0f * LOG_A;            // Clenshaw adds 0.5*coef[0]
        float rk = 1.0f;
        for (int k = 1; k < NCHEB; ++k) {
            rk *= CH_R;
            coef[k] = -2.0f * rk / (float)k;
        }
    }
    if (tid < 196) {
        int i = tid / 14, j = tid % 14;
        float acc = 0.f;
        #pragma unroll
        for (int k = 0; k < 14; ++k) acc = fmaf(w2[i*14 + k], w3[k*14 + j], acc);
        Qm[tid] = acc;
    }
    if (tid < NPAIR) {
        float s = Sin[(size_t)b * SSTRIDE + tid];
        int i = 0, rem = tid;
        while (rem >= HH - i) { rem -= HH - i; ++i; }
        int j = i + rem;
        Sm[i*14 + j] = s;
        Sm[j*14 + i] = s;
    }
    __syncthreads();

    // Y = (2 S - (a+b) I) / (b-a); init Clenshaw buffers
    if (tid < 196) {
        int i = tid / 14, j = tid % 14;
        float d = (i == j) ? 1.f : 0.f;
        Ym[tid] = (2.0f * Sm[tid] - 2.25f * d) * (1.0f / 1.75f);
        Bufs[0][tid] = 0.f;
        Bufs[1][tid] = 0.f;
    }
    __syncthreads();

    // Clenshaw: logm(s1) = 0.5 c0 I + sum c_k T_k(Y)
    int ib1 = 0, ib2 = 1, ibn = 2;
    for (int k = NCHEB - 1; k >= 1; --k) {
        if (tid < 196) {
            int i = tid / 14, j = tid % 14;
            float acc = 0.f;
            #pragma unroll
            for (int kk = 0; kk < 14; ++kk)
                acc = fmaf(Ym[i*14 + kk], Bufs[ib1][kk*14 + j], acc);
            Bufs[ibn][tid] = 2.0f * acc - Bufs[ib2][tid] + ((i == j) ? coef[k] : 0.f);
        }
        __syncthreads();
        int t0 = ib2; ib2 = ib1; ib1 = ibn; ibn = t0;
    }
    if (tid < 196) {
        int i = tid / 14, j = tid % 14;
        float acc = 0.f;
        #pragma unroll
        for (int kk = 0; kk < 14; ++kk)
            acc = fmaf(Ym[i*14 + kk], Bufs[ib1][kk*14 + j], acc);
        Lm[tid] = acc - Bufs[ib2][tid] + ((i == j) ? 0.5f * coef[0] : 0.f);
    }
    __syncthreads();

    // F = Q^T L Q
    if (tid < 196) {
        int i = tid / 14, j = tid % 14;
        float acc = 0.f;
        #pragma unroll
        for (int kk = 0; kk < 14; ++kk)
            acc = fmaf(Lm[i*14 + kk], Qm[kk*14 + j], acc);
        Tm[tid] = acc;
    }
    __syncthreads();
    if (tid < 196) {
        int i = tid / 14, j = tid % 14;
        float acc = 0.f;
        #pragma unroll
        for (int kk = 0; kk < 14; ++kk)
            acc = fmaf(Qm[kk*14 + i], Tm[kk*14 + j], acc);
        Fm[tid] = acc;
    }
    __syncthreads();

    // logits + sigmoid
    float v0 = 0.f, v1 = 0.f;
    if (tid < 196) {
        float f = Fm[tid];
        v0 = f * fcw[tid];
        v1 = f * fcw[196 + tid];
    }
    v0 += __shfl_down(v0, 32, 64);  v1 += __shfl_down(v1, 32, 64);
    v0 += __shfl_down(v0, 16, 64);  v1 += __shfl_down(v1, 16, 64);
    v0 += __shfl_down(v0,  8, 64);  v1 += __shfl_down(v1,  8, 64);
    v0 += __shfl_down(v0,  4, 64);  v1 += __shfl_down(v1,  4, 64);
    v0 += __shfl_down(v0,  2, 64);  v1 += __shfl_down(v1,  2, 64);
    v0 += __shfl_down(v0,  1, 64);  v1 += __shfl_down(v1,  1, 64);
    if (lane == 0) { lpart[wv][0] = v0; lpart[wv][1] = v1; }
    __syncthreads();
    if (tid == 0) {
        float l0 = lpart[0][0] + lpart[1][0] + lpart[2][0] + lpart[3][0] + fcb[0];
        float l1 = lpart[0][1] + lpart[1][1] + lpart[2][1] + lpart[3][1] + fcb[1];
        out[b*2 + 0] = 1.0f / (1.0f + expf(-l0));
        out[b*2 + 1] = 1.0f / (1.0f + expf(-l1));
    }
}

extern "C" void kernel_launch(void* const* d_in, const int* in_sizes, int n_in,
                              void* d_out, int out_size, void* d_ws, size_t ws_size,
                              hipStream_t stream) {
    const float* x   = (const float*)d_in[0];
    const float* w1  = (const float*)d_in[1];
    const float* w2  = (const float*)d_in[2];
    const float* w3  = (const float*)d_in[3];
    const float* fcw = (const float*)d_in[4];
    const float* fcb = (const float*)d_in[5];
    float* out = (float*)d_out;
    float* Sws = (float*)d_ws;                 // B * SSTRIDE floats
    int B = in_sizes[0] / (CC * TT);
    spd_gram<<<B, 256, 0, stream>>>(x, w1, Sws);
    spd_tail<<<B, 256, 0, stream>>>(Sws, w2, w3, fcw, fcb, out);
}